// Round 1
// baseline (643.325 us; speedup 1.0000x reference)
//
#include <hip/hip_runtime.h>
#include <cstdint>
#include <cstddef>

#define CAP 64
static constexpr int BG = 64;   // number of graphs

// ---------------- adjacency build ----------------
__global__ void k_fill(const int* __restrict__ src, const int* __restrict__ dst,
                       int E, int* __restrict__ cnt, int* __restrict__ slots) {
    int e = blockIdx.x * blockDim.x + threadIdx.x;
    if (e >= E) return;
    int s = src[e];
    if (s < 0) return;
    int d = dst[e];
    int pos = atomicAdd(&cnt[d], 1);
    if (pos < CAP) slots[(size_t)d * CAP + pos] = s;
}

__global__ void k_dis(const int* __restrict__ cnt, float* __restrict__ dis, int N) {
    int i = blockIdx.x * blockDim.x + threadIdx.x;
    if (i < N) dis[i] = rsqrtf((float)(cnt[i] + 1));
}

// ---------------- GEMM: h = x @ W  (f32, LDS tiled) ----------------
template<int K, int OUT>
__global__ __launch_bounds__(256) void k_gemm(const float* __restrict__ x,
                                              const float* __restrict__ W,
                                              float* __restrict__ h, int N) {
    constexpr int ROWS = 64;
    constexpr int KT   = (K >= 64) ? 64 : K;
    constexpr int TPR  = OUT / 4;       // threads per row (each does 4 cols)
    constexpr int RPI  = 256 / TPR;     // rows per iteration
    constexpr int RITER = ROWS / RPI;
    __shared__ float Ws[KT * OUT];
    __shared__ float xs[ROWS * KT];
    int tid  = threadIdx.x;
    int row0 = blockIdx.x * ROWS;
    int c    = tid % TPR;
    int rr   = tid / TPR;
    float acc[RITER][4];
    for (int ri = 0; ri < RITER; ++ri)
        for (int j = 0; j < 4; ++j) acc[ri][j] = 0.f;

    for (int kt = 0; kt < K; kt += KT) {
        for (int i = tid; i < KT * OUT; i += 256)
            Ws[i] = W[(size_t)(kt + i / OUT) * OUT + (i % OUT)];
        for (int i = tid; i < ROWS * KT; i += 256)
            xs[i] = x[(size_t)(row0 + i / KT) * K + kt + (i % KT)];
        __syncthreads();
        for (int ri = 0; ri < RITER; ++ri) {
            const float* xr = &xs[(rr + ri * RPI) * KT];
            #pragma unroll 8
            for (int k = 0; k < KT; ++k) {
                float xv = xr[k];
                acc[ri][0] += xv * Ws[k * OUT + c];
                acc[ri][1] += xv * Ws[k * OUT + c + TPR];
                acc[ri][2] += xv * Ws[k * OUT + c + 2 * TPR];
                acc[ri][3] += xv * Ws[k * OUT + c + 3 * TPR];
            }
        }
        __syncthreads();
    }
    for (int ri = 0; ri < RITER; ++ri) {
        int row = row0 + rr + ri * RPI;
        float* hr = &h[(size_t)row * OUT + c];
        hr[0 * TPR] = acc[ri][0];
        hr[1 * TPR] = acc[ri][1];
        hr[2 * TPR] = acc[ri][2];
        hr[3 * TPR] = acc[ri][3];
    }
}

// ---------------- combine: out = relu(agg + h*dis^2 + b) ----------------
template<int OUT>
__global__ __launch_bounds__(256) void k_combine(const float* __restrict__ h,
                                                 const float* __restrict__ dis,
                                                 const int* __restrict__ cnt,
                                                 const int* __restrict__ slots,
                                                 const float* __restrict__ b,
                                                 float* __restrict__ out, int N) {
    constexpr int G = 256 / OUT;
    int f = threadIdx.x % OUT;
    int g = threadIdx.x / OUT;
    int i = blockIdx.x * G + g;
    if (i >= N) return;
    float di = dis[i];
    int c = cnt[i];
    if (c > CAP) c = CAP;
    float acc = h[(size_t)i * OUT + f] * di * di + b[f];
    const int* sl = &slots[(size_t)i * CAP];
    for (int j = 0; j < c; ++j) {
        int s = sl[j];
        acc += h[(size_t)s * OUT + f] * (dis[s] * di);
    }
    out[(size_t)i * OUT + f] = fmaxf(acc, 0.f);
}

// ---------------- scores: tanh((x . pw)/||pw||) ----------------
template<int DIM>
__global__ void k_score(const float* __restrict__ x, const float* __restrict__ pw,
                        float* __restrict__ score, int N) {
    int wave = threadIdx.x >> 6;
    int lane = threadIdx.x & 63;
    int node = blockIdx.x * (blockDim.x >> 6) + wave;
    if (node >= N) return;
    float sd = 0.f, sn = 0.f;
    for (int k = lane; k < DIM; k += 64) {
        float w = pw[k];
        sd += x[(size_t)node * DIM + k] * w;
        sn += w * w;
    }
    #pragma unroll
    for (int off = 32; off > 0; off >>= 1) {
        sd += __shfl_down(sd, off);
        sn += __shfl_down(sn, off);
    }
    if (lane == 0) score[node] = tanhf(sd * rsqrtf(sn));
}

// ---------------- top-k pool (per-graph bitonic sort in LDS) ----------------
template<int n, int DIM>
__global__ void k_topk(const float* __restrict__ score, const float* __restrict__ x,
                       float* __restrict__ xnew, int* __restrict__ newid) {
    constexpr int k = n / 2;
    __shared__ float ss[n];
    __shared__ int   si[n];
    int g = blockIdx.x;
    int t = threadIdx.x;                    // 0 .. n/2-1
    for (int i = t; i < n; i += n / 2) {
        ss[i] = score[g * n + i];
        si[i] = i;
        newid[g * n + i] = -1;
    }
    for (int size = 2; size <= n; size <<= 1) {
        for (int stride = size >> 1; stride > 0; stride >>= 1) {
            __syncthreads();
            int lo = 2 * t - (t & (stride - 1));
            int hi = lo + stride;
            float sa = ss[lo], sb = ss[hi];
            int   ia = si[lo], ib = si[hi];
            bool aFirst = (sa > sb) || (sa == sb && ia < ib);  // desc order, idx tiebreak
            bool desc = ((lo & size) == 0);
            if (desc ? !aFirst : aFirst) {
                ss[lo] = sb; ss[hi] = sa;
                si[lo] = ib; si[hi] = ia;
            }
        }
    }
    __syncthreads();
    for (int r = t; r < k; r += n / 2)
        newid[g * n + si[r]] = g * k + r;
    for (int i = t; i < k * DIM; i += n / 2) {
        int r = i / DIM, f = i % DIM;
        xnew[(size_t)(g * k + r) * DIM + f] =
            x[(size_t)(g * n + si[r]) * DIM + f] * ss[r];
    }
}

// ---------------- edge remap ----------------
__global__ void k_remap(const int* __restrict__ so, const int* __restrict__ dο,
                        const int* __restrict__ newid, int E,
                        int* __restrict__ sn, int* __restrict__ dn) {
    int e = blockIdx.x * blockDim.x + threadIdx.x;
    if (e >= E) return;
    int s = so[e];
    int outS = -1, outD = -1;
    if (s >= 0) {
        int ns = newid[s];
        int nd = newid[dο[e]];
        if (ns >= 0 && nd >= 0) { outS = ns; outD = nd; }
    }
    sn[e] = outS;
    dn[e] = outD;
}

// ---------------- final: per-graph mean -> linear -> *100 ----------------
__global__ void k_final(const float* __restrict__ x, const float* __restrict__ linW,
                        const float* __restrict__ linb, float* __restrict__ out) {
    int g = blockIdx.x;
    int t = threadIdx.x;                    // 128 threads = 128 nodes/graph
    const float* xr = &x[(size_t)(g * 128 + t) * 16];
    float p = 0.f;
    #pragma unroll
    for (int f = 0; f < 16; ++f) p += xr[f] * linW[f];
    #pragma unroll
    for (int off = 32; off > 0; off >>= 1) p += __shfl_down(p, off);
    __shared__ float wsum[2];
    if ((t & 63) == 0) wsum[t >> 6] = p;
    __syncthreads();
    if (t == 0) out[g] = ((wsum[0] + wsum[1]) * (1.f / 128.f) + linb[0]) * 100.f;
}

// ---------------- launch ----------------
extern "C" void kernel_launch(void* const* d_in, const int* in_sizes, int n_in,
                              void* d_out, int out_size, void* d_ws, size_t ws_size,
                              hipStream_t stream) {
    const float* x0  = (const float*)d_in[0];
    const int*   ei  = (const int*)d_in[1];
    const int    E   = in_sizes[1] / 2;
    const int    N0  = in_sizes[0] / 128;   // 65536
    const float* W1  = (const float*)d_in[3];
    const float* b1  = (const float*)d_in[4];
    const float* pw1 = (const float*)d_in[5];
    const float* W2  = (const float*)d_in[6];
    const float* b2  = (const float*)d_in[7];
    const float* pw2 = (const float*)d_in[8];
    const float* W3  = (const float*)d_in[9];
    const float* b3  = (const float*)d_in[10];
    const float* pw3 = (const float*)d_in[11];
    const float* W4  = (const float*)d_in[12];
    const float* b4  = (const float*)d_in[13];
    const float* linW = (const float*)d_in[14];
    const float* linb = (const float*)d_in[15];

    char* ws = (char*)d_ws;
    size_t off = 0;
    float* A     = (float*)(ws + off); off += (size_t)N0 * 128 * 4;      // 32 MB
    float* H     = (float*)(ws + off); off += (size_t)N0 * 128 * 4;      // 32 MB
    float* Bb    = (float*)(ws + off); off += (size_t)(N0 / 2) * 128 * 4; // 16 MB
    int*   slots = (int*)(ws + off);   off += (size_t)N0 * CAP * 4;      // 16 MB
    int*   cnt   = (int*)(ws + off);   off += (size_t)N0 * 4;
    float* dis   = (float*)(ws + off); off += (size_t)N0 * 4;
    float* score = (float*)(ws + off); off += (size_t)N0 * 4;
    int*   newid = (int*)(ws + off);   off += (size_t)N0 * 4;
    int*   e1s   = (int*)(ws + off);   off += (size_t)E * 4;
    int*   e1d   = (int*)(ws + off);   off += (size_t)E * 4;
    int*   e2s   = (int*)(ws + off);   off += (size_t)E * 4;
    int*   e2d   = (int*)(ws + off);   off += (size_t)E * 4;

    const int* src0 = ei;
    const int* dst0 = ei + E;

    // ---- conv1: [N0,128] @ [128,128] ----
    hipMemsetAsync(cnt, 0, (size_t)N0 * 4, stream);
    k_fill<<<E / 256, 256, 0, stream>>>(src0, dst0, E, cnt, slots);
    k_dis<<<N0 / 256, 256, 0, stream>>>(cnt, dis, N0);
    k_gemm<128, 128><<<N0 / 64, 256, 0, stream>>>(x0, W1, H, N0);
    k_combine<128><<<N0 / 2, 256, 0, stream>>>(H, dis, cnt, slots, b1, A, N0);

    // ---- pool1: n=1024 -> 512/graph ----
    k_score<128><<<N0 / 4, 256, 0, stream>>>(A, pw1, score, N0);
    k_topk<1024, 128><<<BG, 512, 0, stream>>>(score, A, Bb, newid);
    k_remap<<<E / 256, 256, 0, stream>>>(src0, dst0, newid, E, e1s, e1d);

    const int N1 = N0 / 2;  // 32768
    // ---- conv2: [N1,128] @ [128,64] ----
    hipMemsetAsync(cnt, 0, (size_t)N1 * 4, stream);
    k_fill<<<E / 256, 256, 0, stream>>>(e1s, e1d, E, cnt, slots);
    k_dis<<<N1 / 256, 256, 0, stream>>>(cnt, dis, N1);
    k_gemm<128, 64><<<N1 / 64, 256, 0, stream>>>(Bb, W2, H, N1);
    k_combine<64><<<N1 / 4, 256, 0, stream>>>(H, dis, cnt, slots, b2, A, N1);

    // ---- pool2: n=512 -> 256/graph ----
    k_score<64><<<N1 / 4, 256, 0, stream>>>(A, pw2, score, N1);
    k_topk<512, 64><<<BG, 256, 0, stream>>>(score, A, Bb, newid);
    k_remap<<<E / 256, 256, 0, stream>>>(e1s, e1d, newid, E, e2s, e2d);

    const int N2 = N1 / 2;  // 16384
    // ---- conv3: [N2,64] @ [64,32] ----
    hipMemsetAsync(cnt, 0, (size_t)N2 * 4, stream);
    k_fill<<<E / 256, 256, 0, stream>>>(e2s, e2d, E, cnt, slots);
    k_dis<<<N2 / 256, 256, 0, stream>>>(cnt, dis, N2);
    k_gemm<64, 32><<<N2 / 64, 256, 0, stream>>>(Bb, W3, H, N2);
    k_combine<32><<<N2 / 8, 256, 0, stream>>>(H, dis, cnt, slots, b3, A, N2);

    // ---- pool3: n=256 -> 128/graph ----
    k_score<32><<<N2 / 4, 256, 0, stream>>>(A, pw3, score, N2);
    k_topk<256, 32><<<BG, 128, 0, stream>>>(score, A, Bb, newid);
    k_remap<<<E / 256, 256, 0, stream>>>(e2s, e2d, newid, E, e1s, e1d);

    const int N3 = N2 / 2;  // 8192
    // ---- conv4: [N3,32] @ [32,16] ----
    hipMemsetAsync(cnt, 0, (size_t)N3 * 4, stream);
    k_fill<<<E / 256, 256, 0, stream>>>(e1s, e1d, E, cnt, slots);
    k_dis<<<N3 / 256, 256, 0, stream>>>(cnt, dis, N3);
    k_gemm<32, 16><<<N3 / 64, 256, 0, stream>>>(Bb, W4, H, N3);
    k_combine<16><<<N3 / 16, 256, 0, stream>>>(H, dis, cnt, slots, b4, A, N3);

    // ---- final: mean-pool + linear ----
    k_final<<<BG, 128, 0, stream>>>(A, linW, linb, (float*)d_out);
}

// Round 3
// 438.951 us; speedup vs baseline: 1.4656x; 1.4656x over previous
//
#include <hip/hip_runtime.h>
#include <cstdint>
#include <cstddef>

#define CAP 64
static constexpr int BG = 64;   // number of graphs

// ---------------- adjacency build ----------------
__global__ void k_fill(const int* __restrict__ src, const int* __restrict__ dst,
                       int E, int* __restrict__ cnt, int* __restrict__ slots) {
    int e = blockIdx.x * blockDim.x + threadIdx.x;
    if (e >= E) return;
    int s = src[e];
    if (s < 0) return;
    int d = dst[e];
    int pos = atomicAdd(&cnt[d], 1);
    if (pos < CAP) slots[(size_t)d * CAP + pos] = s;
}

__global__ void k_dis(const int* __restrict__ cnt, float* __restrict__ dis, int N) {
    int i = blockIdx.x * blockDim.x + threadIdx.x;
    if (i < N) dis[i] = rsqrtf((float)(cnt[i] + 1));
}

// ---------------- GEMM: h = x @ W  (f32, LDS tiled, reg-blocked) ----------------
template<int K, int OUT>
__global__ __launch_bounds__(256) void k_gemm(const float* __restrict__ x,
                                              const float* __restrict__ W,
                                              float* __restrict__ h, int N) {
    constexpr int ROWS = 64;
    constexpr int KT   = (K >= 64) ? 64 : K;
    constexpr int CT   = OUT / 4;       // col-thread count; thread covers cols 4c..4c+3
    constexpr int RT   = 256 / CT;      // row-thread count
    constexpr int RPT  = ROWS / RT;     // rows per thread (contiguous)
    constexpr int XP   = ROWS + 4;      // padded row stride for xs (16B-aligned, bank-spread)
    __shared__ float Ws[KT * OUT];
    __shared__ float xs[KT * XP];       // transposed: xs[k*XP + r]
    int tid  = threadIdx.x;
    int row0 = blockIdx.x * ROWS;
    int c    = tid % CT;
    int rt   = tid / CT;
    float acc[RPT][4];
    for (int r = 0; r < RPT; ++r)
        for (int j = 0; j < 4; ++j) acc[r][j] = 0.f;

    for (int kt = 0; kt < K; kt += KT) {
        for (int i = tid; i < KT * OUT; i += 256)
            Ws[i] = W[(size_t)(kt + i / OUT) * OUT + (i % OUT)];
        for (int i = tid; i < ROWS * KT; i += 256) {
            int r = i / KT, k = i % KT;
            xs[k * XP + r] = x[(size_t)(row0 + r) * K + kt + k];
        }
        __syncthreads();
        for (int k = 0; k < KT; ++k) {
            float4 wv = *(const float4*)&Ws[k * OUT + 4 * c];
            const float* xk = &xs[k * XP + rt * RPT];
            if constexpr (RPT % 4 == 0) {
                #pragma unroll
                for (int rq = 0; rq < RPT / 4; ++rq) {
                    float4 xv4 = *(const float4*)&xk[rq * 4];
                    float xv_[4] = {xv4.x, xv4.y, xv4.z, xv4.w};
                    #pragma unroll
                    for (int r = 0; r < 4; ++r) {
                        float xv = xv_[r];
                        acc[rq * 4 + r][0] += xv * wv.x;
                        acc[rq * 4 + r][1] += xv * wv.y;
                        acc[rq * 4 + r][2] += xv * wv.z;
                        acc[rq * 4 + r][3] += xv * wv.w;
                    }
                }
            } else {
                #pragma unroll
                for (int r = 0; r < RPT; ++r) {
                    float xv = xk[r];
                    acc[r][0] += xv * wv.x;
                    acc[r][1] += xv * wv.y;
                    acc[r][2] += xv * wv.z;
                    acc[r][3] += xv * wv.w;
                }
            }
        }
        __syncthreads();
    }
    for (int r = 0; r < RPT; ++r) {
        int row = row0 + rt * RPT + r;
        float4 o;
        o.x = acc[r][0]; o.y = acc[r][1]; o.z = acc[r][2]; o.w = acc[r][3];
        *(float4*)&h[(size_t)row * OUT + 4 * c] = o;
    }
}

// ---------------- combine: out = relu(agg + h*dis^2 + b), float4/thread ----------------
template<int OUT>
__global__ __launch_bounds__(256) void k_combine4(const float* __restrict__ h,
                                                  const float* __restrict__ dis,
                                                  const int* __restrict__ cnt,
                                                  const int* __restrict__ slots,
                                                  const float* __restrict__ b,
                                                  float* __restrict__ out, int nblocks) {
    constexpr int TPN = OUT / 4;        // threads per node
    constexpr int NPB = 256 / TPN;      // nodes per block
    constexpr int S4  = OUT / 4;        // float4 row stride
    int bid = (int)blockIdx.x;
    int wb  = (bid & 7) * (nblocks >> 3) + (bid >> 3);   // XCD-grouped swizzle
    int i   = wb * NPB + (int)threadIdx.x / TPN;
    int fq  = (int)threadIdx.x % TPN;
    const float4* h4 = (const float4*)h;
    float di = dis[i];
    int c = cnt[i];
    if (c > CAP) c = CAP;
    float4 hv = h4[(size_t)i * S4 + fq];
    float4 bv = *(const float4*)(b + 4 * fq);
    float4 acc;
    acc.x = hv.x * di * di + bv.x;
    acc.y = hv.y * di * di + bv.y;
    acc.z = hv.z * di * di + bv.z;
    acc.w = hv.w * di * di + bv.w;
    const int* sl = &slots[(size_t)i * CAP];
    int j = 0;
    for (; j + 4 <= c; j += 4) {
        int4 s4 = *(const int4*)(sl + j);
        float c0 = dis[s4.x] * di;
        float c1 = dis[s4.y] * di;
        float c2 = dis[s4.z] * di;
        float c3 = dis[s4.w] * di;
        float4 v0 = h4[(size_t)s4.x * S4 + fq];
        float4 v1 = h4[(size_t)s4.y * S4 + fq];
        float4 v2 = h4[(size_t)s4.z * S4 + fq];
        float4 v3 = h4[(size_t)s4.w * S4 + fq];
        acc.x += v0.x * c0; acc.y += v0.y * c0; acc.z += v0.z * c0; acc.w += v0.w * c0;
        acc.x += v1.x * c1; acc.y += v1.y * c1; acc.z += v1.z * c1; acc.w += v1.w * c1;
        acc.x += v2.x * c2; acc.y += v2.y * c2; acc.z += v2.z * c2; acc.w += v2.w * c2;
        acc.x += v3.x * c3; acc.y += v3.y * c3; acc.z += v3.z * c3; acc.w += v3.w * c3;
    }
    for (; j < c; ++j) {
        int s = sl[j];
        float co = dis[s] * di;
        float4 v = h4[(size_t)s * S4 + fq];
        acc.x += v.x * co; acc.y += v.y * co; acc.z += v.z * co; acc.w += v.w * co;
    }
    float4 o;
    o.x = fmaxf(acc.x, 0.f);
    o.y = fmaxf(acc.y, 0.f);
    o.z = fmaxf(acc.z, 0.f);
    o.w = fmaxf(acc.w, 0.f);
    ((float4*)out)[(size_t)i * S4 + fq] = o;
}

// ---------------- scores: tanh((x . pw)/||pw||) (unchanged numerics) ----------------
template<int DIM>
__global__ void k_score(const float* __restrict__ x, const float* __restrict__ pw,
                        float* __restrict__ score, int N) {
    int wave = threadIdx.x >> 6;
    int lane = threadIdx.x & 63;
    int node = blockIdx.x * (blockDim.x >> 6) + wave;
    if (node >= N) return;
    float sd = 0.f, sn = 0.f;
    for (int k = lane; k < DIM; k += 64) {
        float w = pw[k];
        sd += x[(size_t)node * DIM + k] * w;
        sn += w * w;
    }
    #pragma unroll
    for (int off = 32; off > 0; off >>= 1) {
        sd += __shfl_down(sd, off);
        sn += __shfl_down(sn, off);
    }
    if (lane == 0) score[node] = tanhf(sd * rsqrtf(sn));
}

// ---------------- top-k sort (per-graph bitonic in LDS) ----------------
template<int n>
__global__ void k_topk_sort(const float* __restrict__ score,
                            float* __restrict__ kvals, int* __restrict__ kperm,
                            int* __restrict__ newid) {
    constexpr int k = n / 2;
    __shared__ float ss[n];
    __shared__ int   si[n];
    int g = blockIdx.x;
    int t = threadIdx.x;                    // 0 .. n/2-1
    for (int i = t; i < n; i += n / 2) {
        ss[i] = score[g * n + i];
        si[i] = i;
        newid[g * n + i] = -1;
    }
    for (int size = 2; size <= n; size <<= 1) {
        for (int stride = size >> 1; stride > 0; stride >>= 1) {
            __syncthreads();
            int lo = 2 * t - (t & (stride - 1));
            int hi = lo + stride;
            float sa = ss[lo], sb = ss[hi];
            int   ia = si[lo], ib = si[hi];
            bool aFirst = (sa > sb) || (sa == sb && ia < ib);  // desc, idx tiebreak
            bool desc = ((lo & size) == 0);
            if (desc ? !aFirst : aFirst) {
                ss[lo] = sb; ss[hi] = sa;
                si[lo] = ib; si[hi] = ia;
            }
        }
    }
    __syncthreads();
    for (int r = t; r < k; r += n / 2) {
        newid[g * n + si[r]] = g * k + r;
        kperm[g * k + r] = g * n + si[r];   // global source row
        kvals[g * k + r] = ss[r];
    }
}

// ---------------- gather + scale rows (wide) ----------------
template<int DIM>
__global__ void k_gather_scale(const float* __restrict__ x, const int* __restrict__ kperm,
                               const float* __restrict__ kvals, float* __restrict__ xnew,
                               int total4) {
    int idx = blockIdx.x * 256 + threadIdx.x;
    if (idx >= total4) return;
    constexpr int S4 = DIM / 4;
    int row = idx / S4, fq = idx % S4;
    float4 v = ((const float4*)x)[(size_t)kperm[row] * S4 + fq];
    float s = kvals[row];
    float4 o;
    o.x = v.x * s; o.y = v.y * s; o.z = v.z * s; o.w = v.w * s;
    ((float4*)xnew)[(size_t)row * S4 + fq] = o;
}

// ---------------- edge remap ----------------
__global__ void k_remap(const int* __restrict__ so, const int* __restrict__ dd,
                        const int* __restrict__ newid, int E,
                        int* __restrict__ sn, int* __restrict__ dn) {
    int e = blockIdx.x * blockDim.x + threadIdx.x;
    if (e >= E) return;
    int s = so[e];
    int outS = -1, outD = -1;
    if (s >= 0) {
        int ns = newid[s];
        int nd = newid[dd[e]];
        if (ns >= 0 && nd >= 0) { outS = ns; outD = nd; }
    }
    sn[e] = outS;
    dn[e] = outD;
}

// ---------------- final: per-graph mean -> linear -> *100 ----------------
__global__ void k_final(const float* __restrict__ x, const float* __restrict__ linW,
                        const float* __restrict__ linb, float* __restrict__ out) {
    int g = blockIdx.x;
    int t = threadIdx.x;                    // 128 threads = 128 nodes/graph
    const float* xr = &x[(size_t)(g * 128 + t) * 16];
    float p = 0.f;
    #pragma unroll
    for (int f = 0; f < 16; ++f) p += xr[f] * linW[f];
    #pragma unroll
    for (int off = 32; off > 0; off >>= 1) p += __shfl_down(p, off);
    __shared__ float wsum[2];
    if ((t & 63) == 0) wsum[t >> 6] = p;
    __syncthreads();
    if (t == 0) out[g] = ((wsum[0] + wsum[1]) * (1.f / 128.f) + linb[0]) * 100.f;
}

// ---------------- launch ----------------
extern "C" void kernel_launch(void* const* d_in, const int* in_sizes, int n_in,
                              void* d_out, int out_size, void* d_ws, size_t ws_size,
                              hipStream_t stream) {
    const float* x0  = (const float*)d_in[0];
    const int*   ei  = (const int*)d_in[1];
    const int    E   = in_sizes[1] / 2;
    const int    N0  = in_sizes[0] / 128;   // 65536
    const float* W1  = (const float*)d_in[3];
    const float* b1  = (const float*)d_in[4];
    const float* pw1 = (const float*)d_in[5];
    const float* W2  = (const float*)d_in[6];
    const float* b2  = (const float*)d_in[7];
    const float* pw2 = (const float*)d_in[8];
    const float* W3  = (const float*)d_in[9];
    const float* b3  = (const float*)d_in[10];
    const float* pw3 = (const float*)d_in[11];
    const float* W4  = (const float*)d_in[12];
    const float* b4  = (const float*)d_in[13];
    const float* linW = (const float*)d_in[14];
    const float* linb = (const float*)d_in[15];

    char* ws = (char*)d_ws;
    size_t off = 0;
    float* A     = (float*)(ws + off); off += (size_t)N0 * 128 * 4;      // 32 MB
    float* H     = (float*)(ws + off); off += (size_t)N0 * 128 * 4;      // 32 MB
    float* Bb    = (float*)(ws + off); off += (size_t)(N0 / 2) * 128 * 4; // 16 MB
    int*   slots = (int*)(ws + off);   off += (size_t)N0 * CAP * 4;      // 16 MB
    int*   cnt   = (int*)(ws + off);   off += (size_t)N0 * 4;
    float* dis   = (float*)(ws + off); off += (size_t)N0 * 4;
    float* score = (float*)(ws + off); off += (size_t)N0 * 4;
    int*   newid = (int*)(ws + off);   off += (size_t)N0 * 4;
    int*   e1s   = (int*)(ws + off);   off += (size_t)E * 4;
    int*   e1d   = (int*)(ws + off);   off += (size_t)E * 4;
    int*   e2s   = (int*)(ws + off);   off += (size_t)E * 4;
    int*   e2d   = (int*)(ws + off);   off += (size_t)E * 4;
    int*   kperm = (int*)(ws + off);   off += (size_t)(N0 / 2) * 4;
    float* kvals = (float*)(ws + off); off += (size_t)(N0 / 2) * 4;

    const int* src0 = ei;
    const int* dst0 = ei + E;

    // ---- conv1: [N0,128] @ [128,128] ----
    hipMemsetAsync(cnt, 0, (size_t)N0 * 4, stream);
    k_fill<<<E / 256, 256, 0, stream>>>(src0, dst0, E, cnt, slots);
    k_dis<<<N0 / 256, 256, 0, stream>>>(cnt, dis, N0);
    k_gemm<128, 128><<<N0 / 64, 256, 0, stream>>>(x0, W1, H, N0);
    k_combine4<128><<<N0 / 8, 256, 0, stream>>>(H, dis, cnt, slots, b1, A, N0 / 8);

    // ---- pool1: n=1024 -> 512/graph ----
    k_score<128><<<N0 / 4, 256, 0, stream>>>(A, pw1, score, N0);
    k_topk_sort<1024><<<BG, 512, 0, stream>>>(score, kvals, kperm, newid);
    k_gather_scale<128><<<(N0 / 2 * 32 + 255) / 256, 256, 0, stream>>>(A, kperm, kvals, Bb, N0 / 2 * 32);
    k_remap<<<E / 256, 256, 0, stream>>>(src0, dst0, newid, E, e1s, e1d);

    const int N1 = N0 / 2;  // 32768
    // ---- conv2: [N1,128] @ [128,64] ----
    hipMemsetAsync(cnt, 0, (size_t)N1 * 4, stream);
    k_fill<<<E / 256, 256, 0, stream>>>(e1s, e1d, E, cnt, slots);
    k_dis<<<N1 / 256, 256, 0, stream>>>(cnt, dis, N1);
    k_gemm<128, 64><<<N1 / 64, 256, 0, stream>>>(Bb, W2, H, N1);
    k_combine4<64><<<N1 / 16, 256, 0, stream>>>(H, dis, cnt, slots, b2, A, N1 / 16);

    // ---- pool2: n=512 -> 256/graph ----
    k_score<64><<<N1 / 4, 256, 0, stream>>>(A, pw2, score, N1);
    k_topk_sort<512><<<BG, 256, 0, stream>>>(score, kvals, kperm, newid);
    k_gather_scale<64><<<(N1 / 2 * 16 + 255) / 256, 256, 0, stream>>>(A, kperm, kvals, Bb, N1 / 2 * 16);
    k_remap<<<E / 256, 256, 0, stream>>>(e1s, e1d, newid, E, e2s, e2d);

    const int N2 = N1 / 2;  // 16384
    // ---- conv3: [N2,64] @ [64,32] ----
    hipMemsetAsync(cnt, 0, (size_t)N2 * 4, stream);
    k_fill<<<E / 256, 256, 0, stream>>>(e2s, e2d, E, cnt, slots);
    k_dis<<<N2 / 256, 256, 0, stream>>>(cnt, dis, N2);
    k_gemm<64, 32><<<N2 / 64, 256, 0, stream>>>(Bb, W3, H, N2);
    k_combine4<32><<<N2 / 32, 256, 0, stream>>>(H, dis, cnt, slots, b3, A, N2 / 32);

    // ---- pool3: n=256 -> 128/graph ----
    k_score<32><<<N2 / 4, 256, 0, stream>>>(A, pw3, score, N2);
    k_topk_sort<256><<<BG, 128, 0, stream>>>(score, kvals, kperm, newid);
    k_gather_scale<32><<<(N2 / 2 * 8 + 255) / 256, 256, 0, stream>>>(A, kperm, kvals, Bb, N2 / 2 * 8);
    k_remap<<<E / 256, 256, 0, stream>>>(e2s, e2d, newid, E, e1s, e1d);

    const int N3 = N2 / 2;  // 8192
    // ---- conv4: [N3,32] @ [32,16] ----
    hipMemsetAsync(cnt, 0, (size_t)N3 * 4, stream);
    k_fill<<<E / 256, 256, 0, stream>>>(e1s, e1d, E, cnt, slots);
    k_dis<<<N3 / 256, 256, 0, stream>>>(cnt, dis, N3);
    k_gemm<32, 16><<<N3 / 64, 256, 0, stream>>>(Bb, W4, H, N3);
    k_combine4<16><<<N3 / 64, 256, 0, stream>>>(H, dis, cnt, slots, b4, A, N3 / 64);

    // ---- final: mean-pool + linear ----
    k_final<<<BG, 128, 0, stream>>>(A, linW, linb, (float*)d_out);
}

// Round 4
// 367.818 us; speedup vs baseline: 1.7490x; 1.1934x over previous
//
#include <hip/hip_runtime.h>
#include <cstdint>
#include <cstddef>

#define CAP 64
#define EC  20480            // per-graph edge bucket capacity (expected 16384, sigma~124)
static constexpr int BG = 64;   // number of graphs

// ---------------- conv1 adjacency: bucket edges by graph ----------------
__global__ __launch_bounds__(256) void k_scatter(const int* __restrict__ src,
                                                 const int* __restrict__ dst,
                                                 int* __restrict__ gcur,
                                                 int2* __restrict__ ebuf) {
    __shared__ int lcnt[64], lbase[64], lpos[64];
    int tid = threadIdx.x;
    if (tid < 64) { lcnt[tid] = 0; lpos[tid] = 0; }
    __syncthreads();
    int e0 = (int)blockIdx.x * 1024;
    int ss[4], dd[4], gg[4];
    #pragma unroll
    for (int i = 0; i < 4; ++i) {
        int e = e0 + i * 256 + tid;
        ss[i] = src[e]; dd[i] = dst[e];
        gg[i] = dd[i] >> 10;
        atomicAdd(&lcnt[gg[i]], 1);
    }
    __syncthreads();
    if (tid < 64) lbase[tid] = atomicAdd(&gcur[tid], lcnt[tid]);
    __syncthreads();
    #pragma unroll
    for (int i = 0; i < 4; ++i) {
        int p = atomicAdd(&lpos[gg[i]], 1);
        int pos = lbase[gg[i]] + p;
        if (pos < EC) ebuf[(size_t)gg[i] * EC + pos] = make_int2(ss[i], dd[i]);
    }
}

// ---------------- conv1 adjacency: per-graph slot build (LDS counters) ----------------
__global__ __launch_bounds__(1024) void k_build(const int2* __restrict__ ebuf,
                                                const int* __restrict__ gcur,
                                                int* __restrict__ cnt,
                                                int* __restrict__ slots) {
    __shared__ int lc[1024];
    int g = (int)blockIdx.x, tid = (int)threadIdx.x;
    lc[tid] = 0;
    __syncthreads();
    int ec = gcur[g]; if (ec > EC) ec = EC;
    const int2* eb = &ebuf[(size_t)g * EC];
    for (int e = tid; e < ec; e += 1024) {
        int2 sd = eb[e];
        int d = sd.y & 1023;
        int pos = atomicAdd(&lc[d], 1);
        if (pos < CAP) slots[(size_t)(g * 1024 + d) * CAP + pos] = sd.x;
    }
    __syncthreads();
    cnt[g * 1024 + tid] = lc[tid];
}

// ---------------- GEMM: h = x @ W  (f32, LDS tiled, reg-blocked) ----------------
template<int K, int OUT>
__global__ __launch_bounds__(256) void k_gemm(const float* __restrict__ x,
                                              const float* __restrict__ W,
                                              float* __restrict__ h, int N) {
    constexpr int ROWS = 64;
    constexpr int KT   = (K >= 64) ? 64 : K;
    constexpr int CT   = OUT / 4;       // col-thread count; thread covers cols 4c..4c+3
    constexpr int RT   = 256 / CT;      // row-thread count
    constexpr int RPT  = ROWS / RT;     // rows per thread (contiguous)
    constexpr int XP   = ROWS + 4;      // padded row stride for xs
    __shared__ float Ws[KT * OUT];
    __shared__ float xs[KT * XP];       // transposed: xs[k*XP + r]
    int tid  = threadIdx.x;
    int row0 = blockIdx.x * ROWS;
    int c    = tid % CT;
    int rt   = tid / CT;
    float acc[RPT][4];
    for (int r = 0; r < RPT; ++r)
        for (int j = 0; j < 4; ++j) acc[r][j] = 0.f;

    for (int kt = 0; kt < K; kt += KT) {
        for (int i = tid; i < KT * OUT; i += 256)
            Ws[i] = W[(size_t)(kt + i / OUT) * OUT + (i % OUT)];
        for (int i = tid; i < ROWS * KT; i += 256) {
            int r = i / KT, k = i % KT;
            xs[k * XP + r] = x[(size_t)(row0 + r) * K + kt + k];
        }
        __syncthreads();
        for (int k = 0; k < KT; ++k) {
            float4 wv = *(const float4*)&Ws[k * OUT + 4 * c];
            const float* xk = &xs[k * XP + rt * RPT];
            if constexpr (RPT % 4 == 0) {
                #pragma unroll
                for (int rq = 0; rq < RPT / 4; ++rq) {
                    float4 xv4 = *(const float4*)&xk[rq * 4];
                    float xv_[4] = {xv4.x, xv4.y, xv4.z, xv4.w};
                    #pragma unroll
                    for (int r = 0; r < 4; ++r) {
                        float xv = xv_[r];
                        acc[rq * 4 + r][0] += xv * wv.x;
                        acc[rq * 4 + r][1] += xv * wv.y;
                        acc[rq * 4 + r][2] += xv * wv.z;
                        acc[rq * 4 + r][3] += xv * wv.w;
                    }
                }
            } else {
                #pragma unroll
                for (int r = 0; r < RPT; ++r) {
                    float xv = xk[r];
                    acc[r][0] += xv * wv.x;
                    acc[r][1] += xv * wv.y;
                    acc[r][2] += xv * wv.z;
                    acc[r][3] += xv * wv.w;
                }
            }
        }
        __syncthreads();
    }
    for (int r = 0; r < RPT; ++r) {
        int row = row0 + rt * RPT + r;
        float4 o;
        o.x = acc[r][0]; o.y = acc[r][1]; o.z = acc[r][2]; o.w = acc[r][3];
        *(float4*)&h[(size_t)row * OUT + 4 * c] = o;
    }
}

// ---------------- combine: out = relu(agg + h*dis^2 + b), float4/thread ----------------
// dis recomputed as rsqrtf(cnt+1) -- bit-identical to the old dis[] array values.
template<int OUT>
__global__ __launch_bounds__(256) void k_combine4(const float* __restrict__ h,
                                                  const int* __restrict__ cnt,
                                                  const int* __restrict__ slots,
                                                  const float* __restrict__ b,
                                                  float* __restrict__ out, int nblocks) {
    constexpr int TPN = OUT / 4;        // threads per node
    constexpr int NPB = 256 / TPN;      // nodes per block
    constexpr int S4  = OUT / 4;        // float4 row stride
    int bid = (int)blockIdx.x;
    int wb  = (bid & 7) * (nblocks >> 3) + (bid >> 3);   // XCD-grouped swizzle
    int i   = wb * NPB + (int)threadIdx.x / TPN;
    int fq  = (int)threadIdx.x % TPN;
    const float4* h4 = (const float4*)h;
    int ci = cnt[i];
    float di = rsqrtf((float)(ci + 1));
    int c = ci > CAP ? CAP : ci;
    float4 hv = h4[(size_t)i * S4 + fq];
    float4 bv = *(const float4*)(b + 4 * fq);
    float4 acc;
    acc.x = hv.x * di * di + bv.x;
    acc.y = hv.y * di * di + bv.y;
    acc.z = hv.z * di * di + bv.z;
    acc.w = hv.w * di * di + bv.w;
    const int* sl = &slots[(size_t)i * CAP];
    int j = 0;
    for (; j + 4 <= c; j += 4) {
        int4 s4 = *(const int4*)(sl + j);
        float c0 = rsqrtf((float)(cnt[s4.x] + 1)) * di;
        float c1 = rsqrtf((float)(cnt[s4.y] + 1)) * di;
        float c2 = rsqrtf((float)(cnt[s4.z] + 1)) * di;
        float c3 = rsqrtf((float)(cnt[s4.w] + 1)) * di;
        float4 v0 = h4[(size_t)s4.x * S4 + fq];
        float4 v1 = h4[(size_t)s4.y * S4 + fq];
        float4 v2 = h4[(size_t)s4.z * S4 + fq];
        float4 v3 = h4[(size_t)s4.w * S4 + fq];
        acc.x += v0.x * c0; acc.y += v0.y * c0; acc.z += v0.z * c0; acc.w += v0.w * c0;
        acc.x += v1.x * c1; acc.y += v1.y * c1; acc.z += v1.z * c1; acc.w += v1.w * c1;
        acc.x += v2.x * c2; acc.y += v2.y * c2; acc.z += v2.z * c2; acc.w += v2.w * c2;
        acc.x += v3.x * c3; acc.y += v3.y * c3; acc.z += v3.z * c3; acc.w += v3.w * c3;
    }
    for (; j < c; ++j) {
        int s = sl[j];
        float co = rsqrtf((float)(cnt[s] + 1)) * di;
        float4 v = h4[(size_t)s * S4 + fq];
        acc.x += v.x * co; acc.y += v.y * co; acc.z += v.z * co; acc.w += v.w * co;
    }
    float4 o;
    o.x = fmaxf(acc.x, 0.f);
    o.y = fmaxf(acc.y, 0.f);
    o.z = fmaxf(acc.z, 0.f);
    o.w = fmaxf(acc.w, 0.f);
    ((float4*)out)[(size_t)i * S4 + fq] = o;
}

// ---------------- scores: tanh((x . pw)/||pw||) (unchanged numerics) ----------------
template<int DIM>
__global__ void k_score(const float* __restrict__ x, const float* __restrict__ pw,
                        float* __restrict__ score, int N) {
    int wave = threadIdx.x >> 6;
    int lane = threadIdx.x & 63;
    int node = blockIdx.x * (blockDim.x >> 6) + wave;
    if (node >= N) return;
    float sd = 0.f, sn = 0.f;
    for (int k = lane; k < DIM; k += 64) {
        float w = pw[k];
        sd += x[(size_t)node * DIM + k] * w;
        sn += w * w;
    }
    #pragma unroll
    for (int off = 32; off > 0; off >>= 1) {
        sd += __shfl_down(sd, off);
        sn += __shfl_down(sn, off);
    }
    if (lane == 0) score[node] = tanhf(sd * rsqrtf(sn));
}

// ---------------- top-k sort (per-graph bitonic in LDS) ----------------
template<int n>
__global__ void k_topk_sort(const float* __restrict__ score,
                            float* __restrict__ kvals, int* __restrict__ kperm,
                            int* __restrict__ newid) {
    constexpr int k = n / 2;
    __shared__ float ss[n];
    __shared__ int   si[n];
    int g = blockIdx.x;
    int t = threadIdx.x;                    // 0 .. n/2-1
    for (int i = t; i < n; i += n / 2) {
        ss[i] = score[g * n + i];
        si[i] = i;
        newid[g * n + i] = -1;
    }
    for (int size = 2; size <= n; size <<= 1) {
        for (int stride = size >> 1; stride > 0; stride >>= 1) {
            __syncthreads();
            int lo = 2 * t - (t & (stride - 1));
            int hi = lo + stride;
            float sa = ss[lo], sb = ss[hi];
            int   ia = si[lo], ib = si[hi];
            bool aFirst = (sa > sb) || (sa == sb && ia < ib);  // desc, idx tiebreak
            bool desc = ((lo & size) == 0);
            if (desc ? !aFirst : aFirst) {
                ss[lo] = sb; ss[hi] = sa;
                si[lo] = ib; si[hi] = ia;
            }
        }
    }
    __syncthreads();
    for (int r = t; r < k; r += n / 2) {
        newid[g * n + si[r]] = g * k + r;
        kperm[g * k + r] = g * n + si[r];   // global source row (old id)
        kvals[g * k + r] = ss[r];
    }
}

// ---------------- pool post: gather+scale rows AND derive next-layer adjacency ----
template<int DIM>
__global__ __launch_bounds__(256) void k_pool_post(const float* __restrict__ x,
                                                   const int* __restrict__ kperm,
                                                   const float* __restrict__ kvals,
                                                   const int* __restrict__ newid,
                                                   const int* __restrict__ cnt_old,
                                                   const int* __restrict__ slots_old,
                                                   float* __restrict__ xnew,
                                                   int* __restrict__ cnt_new,
                                                   int* __restrict__ slots_new,
                                                   int Nnew) {
    constexpr int S4  = DIM / 4;
    constexpr int RPB = 32;             // rows per block (8 threads per row)
    int r = (int)blockIdx.x * RPB + (int)threadIdx.x / 8;
    int q = (int)threadIdx.x % 8;
    if (r >= Nnew) return;
    int old = kperm[r];
    float s = kvals[r];
    const float4* x4 = (const float4*)x;
    float4* o4 = (float4*)xnew;
    #pragma unroll
    for (int it = 0; it < (S4 + 7) / 8; ++it) {
        int idx = it * 8 + q;
        if (S4 % 8 == 0 || idx < S4) {
            float4 v = x4[(size_t)old * S4 + idx];
            float4 o;
            o.x = v.x * s; o.y = v.y * s; o.z = v.z * s; o.w = v.w * s;
            o4[(size_t)r * S4 + idx] = o;
        }
    }
    if (q == 0) {
        int c = cnt_old[old];
        if (c > CAP) c = CAP;
        const int* sl = &slots_old[(size_t)old * CAP];
        int w = 0;
        for (int j = 0; j < c; ++j) {
            int ns = newid[sl[j]];
            if (ns >= 0) slots_new[(size_t)r * CAP + (w++)] = ns;
        }
        cnt_new[r] = w;
    }
}

// ---------------- final: per-graph mean -> linear -> *100 ----------------
__global__ void k_final(const float* __restrict__ x, const float* __restrict__ linW,
                        const float* __restrict__ linb, float* __restrict__ out) {
    int g = blockIdx.x;
    int t = threadIdx.x;                    // 128 threads = 128 nodes/graph
    const float* xr = &x[(size_t)(g * 128 + t) * 16];
    float p = 0.f;
    #pragma unroll
    for (int f = 0; f < 16; ++f) p += xr[f] * linW[f];
    #pragma unroll
    for (int off = 32; off > 0; off >>= 1) p += __shfl_down(p, off);
    __shared__ float wsum[2];
    if ((t & 63) == 0) wsum[t >> 6] = p;
    __syncthreads();
    if (t == 0) out[g] = ((wsum[0] + wsum[1]) * (1.f / 128.f) + linb[0]) * 100.f;
}

// ---------------- launch ----------------
extern "C" void kernel_launch(void* const* d_in, const int* in_sizes, int n_in,
                              void* d_out, int out_size, void* d_ws, size_t ws_size,
                              hipStream_t stream) {
    const float* x0  = (const float*)d_in[0];
    const int*   ei  = (const int*)d_in[1];
    const int    E   = in_sizes[1] / 2;     // 1048576
    const int    N0  = in_sizes[0] / 128;   // 65536
    const float* W1  = (const float*)d_in[3];
    const float* b1  = (const float*)d_in[4];
    const float* pw1 = (const float*)d_in[5];
    const float* W2  = (const float*)d_in[6];
    const float* b2  = (const float*)d_in[7];
    const float* pw2 = (const float*)d_in[8];
    const float* W3  = (const float*)d_in[9];
    const float* b3  = (const float*)d_in[10];
    const float* pw3 = (const float*)d_in[11];
    const float* W4  = (const float*)d_in[12];
    const float* b4  = (const float*)d_in[13];
    const float* linW = (const float*)d_in[14];
    const float* linb = (const float*)d_in[15];

    char* ws = (char*)d_ws;
    size_t off = 0;
    float* A      = (float*)(ws + off); off += (size_t)N0 * 128 * 4;       // 32 MB
    float* H      = (float*)(ws + off); off += (size_t)N0 * 128 * 4;       // 32 MB
    float* Bb     = (float*)(ws + off); off += (size_t)(N0 / 2) * 128 * 4; // 16 MB
    int*   slotsA = (int*)(ws + off);   off += (size_t)N0 * CAP * 4;       // 16 MB
    int*   slotsB = (int*)(ws + off);   off += (size_t)(N0 / 2) * CAP * 4; // 8 MB
    int2*  ebuf   = (int2*)(ws + off);  off += (size_t)BG * EC * 8;        // 10.5 MB
    int*   cntA   = (int*)(ws + off);   off += (size_t)N0 * 4;
    int*   cntB   = (int*)(ws + off);   off += (size_t)(N0 / 2) * 4;
    float* score  = (float*)(ws + off); off += (size_t)N0 * 4;
    int*   newid  = (int*)(ws + off);   off += (size_t)N0 * 4;
    int*   kperm  = (int*)(ws + off);   off += (size_t)(N0 / 2) * 4;
    float* kvals  = (float*)(ws + off); off += (size_t)(N0 / 2) * 4;
    int*   gcur   = (int*)(ws + off);   off += 64 * 4;

    const int* src0 = ei;
    const int* dst0 = ei + E;

    const int N1 = N0 / 2;   // 32768
    const int N2 = N1 / 2;   // 16384
    const int N3 = N2 / 2;   // 8192

    // ---- conv1 adjacency: bucket by graph, then per-graph LDS build ----
    hipMemsetAsync(gcur, 0, 64 * 4, stream);
    k_scatter<<<E / 1024, 256, 0, stream>>>(src0, dst0, gcur, ebuf);
    k_build<<<BG, 1024, 0, stream>>>(ebuf, gcur, cntA, slotsA);

    // ---- conv1: [N0,128] @ [128,128] ----
    k_gemm<128, 128><<<N0 / 64, 256, 0, stream>>>(x0, W1, H, N0);
    k_combine4<128><<<N0 / 8, 256, 0, stream>>>(H, cntA, slotsA, b1, A, N0 / 8);

    // ---- pool1: n=1024 -> 512/graph ----
    k_score<128><<<N0 / 4, 256, 0, stream>>>(A, pw1, score, N0);
    k_topk_sort<1024><<<BG, 512, 0, stream>>>(score, kvals, kperm, newid);
    k_pool_post<128><<<N1 / 32, 256, 0, stream>>>(A, kperm, kvals, newid,
                                                  cntA, slotsA, Bb, cntB, slotsB, N1);

    // ---- conv2: [N1,128] @ [128,64] ----
    k_gemm<128, 64><<<N1 / 64, 256, 0, stream>>>(Bb, W2, H, N1);
    k_combine4<64><<<N1 / 16, 256, 0, stream>>>(H, cntB, slotsB, b2, A, N1 / 16);

    // ---- pool2: n=512 -> 256/graph ----
    k_score<64><<<N1 / 4, 256, 0, stream>>>(A, pw2, score, N1);
    k_topk_sort<512><<<BG, 256, 0, stream>>>(score, kvals, kperm, newid);
    k_pool_post<64><<<N2 / 32, 256, 0, stream>>>(A, kperm, kvals, newid,
                                                 cntB, slotsB, Bb, cntA, slotsA, N2);

    // ---- conv3: [N2,64] @ [64,32] ----
    k_gemm<64, 32><<<N2 / 64, 256, 0, stream>>>(Bb, W3, H, N2);
    k_combine4<32><<<N2 / 32, 256, 0, stream>>>(H, cntA, slotsA, b3, A, N2 / 32);

    // ---- pool3: n=256 -> 128/graph ----
    k_score<32><<<N2 / 4, 256, 0, stream>>>(A, pw3, score, N2);
    k_topk_sort<256><<<BG, 128, 0, stream>>>(score, kvals, kperm, newid);
    k_pool_post<32><<<N3 / 32, 256, 0, stream>>>(A, kperm, kvals, newid,
                                                 cntA, slotsA, Bb, cntB, slotsB, N3);

    // ---- conv4: [N3,32] @ [32,16] ----
    k_gemm<32, 16><<<N3 / 64, 256, 0, stream>>>(Bb, W4, H, N3);
    k_combine4<16><<<N3 / 64, 256, 0, stream>>>(H, cntB, slotsB, b4, A, N3 / 64);

    // ---- final: mean-pool + linear ----
    k_final<<<BG, 128, 0, stream>>>(A, linW, linb, (float*)d_out);
}

// Round 6
// 346.627 us; speedup vs baseline: 1.8560x; 1.0611x over previous
//
#include <hip/hip_runtime.h>
#include <cstdint>
#include <cstddef>

#define CAP 64
#define EC  20480            // per-graph edge bucket capacity (expected 16384, sigma~124)
static constexpr int BG = 64;   // number of graphs

// ---------------- conv1 adjacency: bucket edges by graph ----------------
__global__ __launch_bounds__(256) void k_scatter(const int* __restrict__ src,
                                                 const int* __restrict__ dst,
                                                 int* __restrict__ gcur,
                                                 int2* __restrict__ ebuf) {
    __shared__ int lcnt[64], lbase[64], lpos[64];
    int tid = threadIdx.x;
    if (tid < 64) { lcnt[tid] = 0; lpos[tid] = 0; }
    __syncthreads();
    int e0 = (int)blockIdx.x * 1024;
    int ss[4], dd[4], gg[4];
    #pragma unroll
    for (int i = 0; i < 4; ++i) {
        int e = e0 + i * 256 + tid;
        ss[i] = src[e]; dd[i] = dst[e];
        gg[i] = dd[i] >> 10;
        atomicAdd(&lcnt[gg[i]], 1);
    }
    __syncthreads();
    if (tid < 64) lbase[tid] = atomicAdd(&gcur[tid], lcnt[tid]);
    __syncthreads();
    #pragma unroll
    for (int i = 0; i < 4; ++i) {
        int p = atomicAdd(&lpos[gg[i]], 1);
        int pos = lbase[gg[i]] + p;
        if (pos < EC) ebuf[(size_t)gg[i] * EC + pos] = make_int2(ss[i], dd[i]);
    }
}

// ---------------- conv1 adjacency: per-graph slot build (LDS counters) ----------------
__global__ __launch_bounds__(1024) void k_build(const int2* __restrict__ ebuf,
                                                const int* __restrict__ gcur,
                                                int* __restrict__ cnt,
                                                int* __restrict__ slots) {
    __shared__ int lc[1024];
    int g = (int)blockIdx.x, tid = (int)threadIdx.x;
    lc[tid] = 0;
    __syncthreads();
    int ec = gcur[g]; if (ec > EC) ec = EC;
    const int2* eb = &ebuf[(size_t)g * EC];
    for (int e = tid; e < ec; e += 1024) {
        int2 sd = eb[e];
        int d = sd.y & 1023;
        int pos = atomicAdd(&lc[d], 1);
        if (pos < CAP) slots[(size_t)(g * 1024 + d) * CAP + pos] = sd.x;
    }
    __syncthreads();
    cnt[g * 1024 + tid] = lc[tid];
}

// ---------------- GEMM v2: 128-row x OUT tile, 512 thr, split-chunk layout ----------
// Bank-conflict-free (<=2-way) LDS access; per-element k-ascending accumulation
// (bitwise identical to previous version).
template<int K, int OUT>
__global__ __launch_bounds__(512) void k_gemm2(const float* __restrict__ x,
                                               const float* __restrict__ W,
                                               float* __restrict__ h, int N) {
    constexpr int KT = 32;
    constexpr int RB = 128;
    constexpr int CC = OUT / 64;            // 2 (OUT=128) or 1 (OUT=64)
    constexpr int NW4 = (KT * OUT / 4) / 512;  // W float4 loads per thread
    __shared__ float Ws[KT * OUT];
    __shared__ float xs[KT * RB];           // transposed: xs[k*RB + row]
    int tid = (int)threadIdx.x;
    int tx = tid & 15;
    int ty = tid >> 4;                      // 0..31
    int row0 = (int)blockIdx.x * RB;
    const float4* W4 = (const float4*)W;

    float acc[4][CC * 4];
    #pragma unroll
    for (int r = 0; r < 4; ++r)
        #pragma unroll
        for (int c = 0; c < CC * 4; ++c) acc[r][c] = 0.f;

    int xr  = tid & 127;                    // staging row
    int xcb = tid >> 7;                     // 0..3 -> which pair of k-chunks

    for (int kt = 0; kt < K; kt += KT) {
        #pragma unroll
        for (int i = 0; i < NW4; ++i) {
            int idx = tid + i * 512;
            ((float4*)Ws)[idx] = W4[(size_t)kt * (OUT / 4) + idx];
        }
        const float4* xrow = (const float4*)(x + (size_t)(row0 + xr) * K + kt);
        #pragma unroll
        for (int i = 0; i < 2; ++i) {
            int c8 = xcb * 2 + i;           // float4 chunk within KT (0..7)
            float4 v = xrow[c8];
            xs[(c8 * 4 + 0) * RB + xr] = v.x;
            xs[(c8 * 4 + 1) * RB + xr] = v.y;
            xs[(c8 * 4 + 2) * RB + xr] = v.z;
            xs[(c8 * 4 + 3) * RB + xr] = v.w;
        }
        __syncthreads();
        #pragma unroll 8
        for (int k = 0; k < KT; ++k) {
            float4 av = *(const float4*)&xs[k * RB + 4 * ty];
            float4 b0 = *(const float4*)&Ws[k * OUT + 4 * tx];
            float a_[4] = {av.x, av.y, av.z, av.w};
            float b_[4] = {b0.x, b0.y, b0.z, b0.w};
            #pragma unroll
            for (int r = 0; r < 4; ++r)
                #pragma unroll
                for (int c = 0; c < 4; ++c)
                    acc[r][c] += a_[r] * b_[c];
            if constexpr (CC == 2) {
                float4 b1 = *(const float4*)&Ws[k * OUT + 64 + 4 * tx];
                float b2_[4] = {b1.x, b1.y, b1.z, b1.w};
                #pragma unroll
                for (int r = 0; r < 4; ++r)
                    #pragma unroll
                    for (int c = 0; c < 4; ++c)
                        acc[r][4 + c] += a_[r] * b2_[c];
            }
        }
        __syncthreads();
    }
    float4* h4 = (float4*)h;
    #pragma unroll
    for (int rr = 0; rr < 4; ++rr) {
        int row = row0 + 4 * ty + rr;
        float4 o0;
        o0.x = acc[rr][0]; o0.y = acc[rr][1]; o0.z = acc[rr][2]; o0.w = acc[rr][3];
        h4[(size_t)row * (OUT / 4) + tx] = o0;
        if constexpr (CC == 2) {
            float4 o1;
            o1.x = acc[rr][4]; o1.y = acc[rr][5]; o1.z = acc[rr][6]; o1.w = acc[rr][7];
            h4[(size_t)row * (OUT / 4) + 16 + tx] = o1;
        }
    }
}

// ---------------- GEMM v1 (kept for small OUT): LDS tiled, reg-blocked ----------------
template<int K, int OUT>
__global__ __launch_bounds__(256) void k_gemm(const float* __restrict__ x,
                                              const float* __restrict__ W,
                                              float* __restrict__ h, int N) {
    constexpr int ROWS = 64;
    constexpr int KT   = (K >= 64) ? 64 : K;
    constexpr int CT   = OUT / 4;
    constexpr int RT   = 256 / CT;
    constexpr int RPT  = ROWS / RT;
    constexpr int XP   = ROWS + 4;
    __shared__ float Ws[KT * OUT];
    __shared__ float xs[KT * XP];
    int tid  = threadIdx.x;
    int row0 = blockIdx.x * ROWS;
    int c    = tid % CT;
    int rt   = tid / CT;
    float acc[RPT][4];
    for (int r = 0; r < RPT; ++r)
        for (int j = 0; j < 4; ++j) acc[r][j] = 0.f;

    for (int kt = 0; kt < K; kt += KT) {
        for (int i = tid; i < KT * OUT; i += 256)
            Ws[i] = W[(size_t)(kt + i / OUT) * OUT + (i % OUT)];
        for (int i = tid; i < ROWS * KT; i += 256) {
            int r = i / KT, k = i % KT;
            xs[k * XP + r] = x[(size_t)(row0 + r) * K + kt + k];
        }
        __syncthreads();
        for (int k = 0; k < KT; ++k) {
            float4 wv = *(const float4*)&Ws[k * OUT + 4 * c];
            const float* xk = &xs[k * XP + rt * RPT];
            #pragma unroll
            for (int r = 0; r < RPT; ++r) {
                float xv = xk[r];
                acc[r][0] += xv * wv.x;
                acc[r][1] += xv * wv.y;
                acc[r][2] += xv * wv.z;
                acc[r][3] += xv * wv.w;
            }
        }
        __syncthreads();
    }
    for (int r = 0; r < RPT; ++r) {
        int row = row0 + rt * RPT + r;
        float4 o;
        o.x = acc[r][0]; o.y = acc[r][1]; o.z = acc[r][2]; o.w = acc[r][3];
        *(float4*)&h[(size_t)row * OUT + 4 * c] = o;
    }
}

// ---------------- combine: out = relu(agg + h*dis^2 + b), float4/thread ----------------
template<int OUT>
__global__ __launch_bounds__(256) void k_combine4(const float* __restrict__ h,
                                                  const int* __restrict__ cnt,
                                                  const int* __restrict__ slots,
                                                  const float* __restrict__ b,
                                                  float* __restrict__ out, int nblocks) {
    constexpr int TPN = OUT / 4;
    constexpr int NPB = 256 / TPN;
    constexpr int S4  = OUT / 4;
    int bid = (int)blockIdx.x;
    int wb  = (bid & 7) * (nblocks >> 3) + (bid >> 3);   // XCD-grouped swizzle
    int i   = wb * NPB + (int)threadIdx.x / TPN;
    int fq  = (int)threadIdx.x % TPN;
    const float4* h4 = (const float4*)h;
    int ci = cnt[i];
    float di = rsqrtf((float)(ci + 1));
    int c = ci > CAP ? CAP : ci;
    float4 hv = h4[(size_t)i * S4 + fq];
    float4 bv = *(const float4*)(b + 4 * fq);
    float4 acc;
    acc.x = hv.x * di * di + bv.x;
    acc.y = hv.y * di * di + bv.y;
    acc.z = hv.z * di * di + bv.z;
    acc.w = hv.w * di * di + bv.w;
    const int* sl = &slots[(size_t)i * CAP];
    int j = 0;
    for (; j + 4 <= c; j += 4) {
        int4 s4 = *(const int4*)(sl + j);
        float c0 = rsqrtf((float)(cnt[s4.x] + 1)) * di;
        float c1 = rsqrtf((float)(cnt[s4.y] + 1)) * di;
        float c2 = rsqrtf((float)(cnt[s4.z] + 1)) * di;
        float c3 = rsqrtf((float)(cnt[s4.w] + 1)) * di;
        float4 v0 = h4[(size_t)s4.x * S4 + fq];
        float4 v1 = h4[(size_t)s4.y * S4 + fq];
        float4 v2 = h4[(size_t)s4.z * S4 + fq];
        float4 v3 = h4[(size_t)s4.w * S4 + fq];
        acc.x += v0.x * c0; acc.y += v0.y * c0; acc.z += v0.z * c0; acc.w += v0.w * c0;
        acc.x += v1.x * c1; acc.y += v1.y * c1; acc.z += v1.z * c1; acc.w += v1.w * c1;
        acc.x += v2.x * c2; acc.y += v2.y * c2; acc.z += v2.z * c2; acc.w += v2.w * c2;
        acc.x += v3.x * c3; acc.y += v3.y * c3; acc.z += v3.z * c3; acc.w += v3.w * c3;
    }
    for (; j < c; ++j) {
        int s = sl[j];
        float co = rsqrtf((float)(cnt[s] + 1)) * di;
        float4 v = h4[(size_t)s * S4 + fq];
        acc.x += v.x * co; acc.y += v.y * co; acc.z += v.z * co; acc.w += v.w * co;
    }
    float4 o;
    o.x = fmaxf(acc.x, 0.f);
    o.y = fmaxf(acc.y, 0.f);
    o.z = fmaxf(acc.z, 0.f);
    o.w = fmaxf(acc.w, 0.f);
    ((float4*)out)[(size_t)i * S4 + fq] = o;
}

// ---------------- scores: tanh((x . pw)/||pw||) (unchanged numerics) ----------------
template<int DIM>
__global__ void k_score(const float* __restrict__ x, const float* __restrict__ pw,
                        float* __restrict__ score, int N) {
    int wave = threadIdx.x >> 6;
    int lane = threadIdx.x & 63;
    int node = blockIdx.x * (blockDim.x >> 6) + wave;
    if (node >= N) return;
    float sd = 0.f, sn = 0.f;
    for (int k = lane; k < DIM; k += 64) {
        float w = pw[k];
        sd += x[(size_t)node * DIM + k] * w;
        sn += w * w;
    }
    #pragma unroll
    for (int off = 32; off > 0; off >>= 1) {
        sd += __shfl_down(sd, off);
        sn += __shfl_down(sn, off);
    }
    if (lane == 0) score[node] = tanhf(sd * rsqrtf(sn));
}

// ---------------- top-k sort (per-graph bitonic in LDS) ----------------
template<int n>
__global__ void k_topk_sort(const float* __restrict__ score,
                            float* __restrict__ kvals, int* __restrict__ kperm,
                            int* __restrict__ newid) {
    constexpr int k = n / 2;
    __shared__ float ss[n];
    __shared__ int   si[n];
    int g = blockIdx.x;
    int t = threadIdx.x;                    // 0 .. n/2-1
    for (int i = t; i < n; i += n / 2) {
        ss[i] = score[g * n + i];
        si[i] = i;
        newid[g * n + i] = -1;
    }
    for (int size = 2; size <= n; size <<= 1) {
        for (int stride = size >> 1; stride > 0; stride >>= 1) {
            __syncthreads();
            int lo = 2 * t - (t & (stride - 1));
            int hi = lo + stride;
            float sa = ss[lo], sb = ss[hi];
            int   ia = si[lo], ib = si[hi];
            bool aFirst = (sa > sb) || (sa == sb && ia < ib);  // desc, idx tiebreak
            bool desc = ((lo & size) == 0);
            if (desc ? !aFirst : aFirst) {
                ss[lo] = sb; ss[hi] = sa;
                si[lo] = ib; si[hi] = ia;
            }
        }
    }
    __syncthreads();
    for (int r = t; r < k; r += n / 2) {
        newid[g * n + si[r]] = g * k + r;
        kperm[g * k + r] = g * n + si[r];   // global source row (old id)
        kvals[g * k + r] = ss[r];
    }
}

// ---------------- pool post: gather+scale rows AND derive next-layer adjacency ----
template<int DIM>
__global__ __launch_bounds__(256) void k_pool_post(const float* __restrict__ x,
                                                   const int* __restrict__ kperm,
                                                   const float* __restrict__ kvals,
                                                   const int* __restrict__ newid,
                                                   const int* __restrict__ cnt_old,
                                                   const int* __restrict__ slots_old,
                                                   float* __restrict__ xnew,
                                                   int* __restrict__ cnt_new,
                                                   int* __restrict__ slots_new,
                                                   int Nnew) {
    constexpr int S4  = DIM / 4;
    constexpr int RPB = 32;             // rows per block (8 threads per row)
    int r = (int)blockIdx.x * RPB + (int)threadIdx.x / 8;
    int q = (int)threadIdx.x % 8;
    if (r >= Nnew) return;
    int old = kperm[r];
    float s = kvals[r];
    const float4* x4 = (const float4*)x;
    float4* o4 = (float4*)xnew;
    #pragma unroll
    for (int it = 0; it < (S4 + 7) / 8; ++it) {
        int idx = it * 8 + q;
        if (S4 % 8 == 0 || idx < S4) {
            float4 v = x4[(size_t)old * S4 + idx];
            float4 o;
            o.x = v.x * s; o.y = v.y * s; o.z = v.z * s; o.w = v.w * s;
            o4[(size_t)r * S4 + idx] = o;
        }
    }
    if (q == 0) {
        int c = cnt_old[old];
        if (c > CAP) c = CAP;
        const int* sl = &slots_old[(size_t)old * CAP];
        int w = 0;
        for (int j = 0; j < c; ++j) {
            int ns = newid[sl[j]];
            if (ns >= 0) slots_new[(size_t)r * CAP + (w++)] = ns;
        }
        cnt_new[r] = w;
    }
}

// ---------------- final: per-graph mean -> linear -> *100 ----------------
__global__ void k_final(const float* __restrict__ x, const float* __restrict__ linW,
                        const float* __restrict__ linb, float* __restrict__ out) {
    int g = blockIdx.x;
    int t = threadIdx.x;                    // 128 threads = 128 nodes/graph
    const float* xr = &x[(size_t)(g * 128 + t) * 16];
    float p = 0.f;
    #pragma unroll
    for (int f = 0; f < 16; ++f) p += xr[f] * linW[f];
    #pragma unroll
    for (int off = 32; off > 0; off >>= 1) p += __shfl_down(p, off);
    __shared__ float wsum[2];
    if ((t & 63) == 0) wsum[t >> 6] = p;
    __syncthreads();
    if (t == 0) out[g] = ((wsum[0] + wsum[1]) * (1.f / 128.f) + linb[0]) * 100.f;
}

// ---------------- launch ----------------
extern "C" void kernel_launch(void* const* d_in, const int* in_sizes, int n_in,
                              void* d_out, int out_size, void* d_ws, size_t ws_size,
                              hipStream_t stream) {
    const float* x0  = (const float*)d_in[0];
    const int*   ei  = (const int*)d_in[1];
    const int    E   = in_sizes[1] / 2;     // 1048576
    const int    N0  = in_sizes[0] / 128;   // 65536
    const float* W1  = (const float*)d_in[3];
    const float* b1  = (const float*)d_in[4];
    const float* pw1 = (const float*)d_in[5];
    const float* W2  = (const float*)d_in[6];
    const float* b2  = (const float*)d_in[7];
    const float* pw2 = (const float*)d_in[8];
    const float* W3  = (const float*)d_in[9];
    const float* b3  = (const float*)d_in[10];
    const float* pw3 = (const float*)d_in[11];
    const float* W4  = (const float*)d_in[12];
    const float* b4  = (const float*)d_in[13];
    const float* linW = (const float*)d_in[14];
    const float* linb = (const float*)d_in[15];

    char* ws = (char*)d_ws;
    size_t off = 0;
    float* A      = (float*)(ws + off); off += (size_t)N0 * 128 * 4;       // 32 MB
    float* H      = (float*)(ws + off); off += (size_t)N0 * 128 * 4;       // 32 MB
    float* Bb     = (float*)(ws + off); off += (size_t)(N0 / 2) * 128 * 4; // 16 MB
    int*   slotsA = (int*)(ws + off);   off += (size_t)N0 * CAP * 4;       // 16 MB
    int*   slotsB = (int*)(ws + off);   off += (size_t)(N0 / 2) * CAP * 4; // 8 MB
    int2*  ebuf   = (int2*)(ws + off);  off += (size_t)BG * EC * 8;        // 10.5 MB
    int*   cntA   = (int*)(ws + off);   off += (size_t)N0 * 4;
    int*   cntB   = (int*)(ws + off);   off += (size_t)(N0 / 2) * 4;
    float* score  = (float*)(ws + off); off += (size_t)N0 * 4;
    int*   newid  = (int*)(ws + off);   off += (size_t)N0 * 4;
    int*   kperm  = (int*)(ws + off);   off += (size_t)(N0 / 2) * 4;
    float* kvals  = (float*)(ws + off); off += (size_t)(N0 / 2) * 4;
    int*   gcur   = (int*)(ws + off);   off += 64 * 4;

    const int* src0 = ei;
    const int* dst0 = ei + E;

    const int N1 = N0 / 2;   // 32768
    const int N2 = N1 / 2;   // 16384
    const int N3 = N2 / 2;   // 8192

    // ---- conv1 adjacency: bucket by graph, then per-graph LDS build ----
    hipMemsetAsync(gcur, 0, 64 * 4, stream);
    k_scatter<<<E / 1024, 256, 0, stream>>>(src0, dst0, gcur, ebuf);
    k_build<<<BG, 1024, 0, stream>>>(ebuf, gcur, cntA, slotsA);

    // ---- conv1: [N0,128] @ [128,128] ----
    k_gemm2<128, 128><<<N0 / 128, 512, 0, stream>>>(x0, W1, H, N0);
    k_combine4<128><<<N0 / 8, 256, 0, stream>>>(H, cntA, slotsA, b1, A, N0 / 8);

    // ---- pool1: n=1024 -> 512/graph ----
    k_score<128><<<N0 / 4, 256, 0, stream>>>(A, pw1, score, N0);
    k_topk_sort<1024><<<BG, 512, 0, stream>>>(score, kvals, kperm, newid);
    k_pool_post<128><<<N1 / 32, 256, 0, stream>>>(A, kperm, kvals, newid,
                                                  cntA, slotsA, Bb, cntB, slotsB, N1);

    // ---- conv2: [N1,128] @ [128,64] ----
    k_gemm2<128, 64><<<N1 / 128, 512, 0, stream>>>(Bb, W2, H, N1);
    k_combine4<64><<<N1 / 16, 256, 0, stream>>>(H, cntB, slotsB, b2, A, N1 / 16);

    // ---- pool2: n=512 -> 256/graph ----
    k_score<64><<<N1 / 4, 256, 0, stream>>>(A, pw2, score, N1);
    k_topk_sort<512><<<BG, 256, 0, stream>>>(score, kvals, kperm, newid);
    k_pool_post<64><<<N2 / 32, 256, 0, stream>>>(A, kperm, kvals, newid,
                                                 cntB, slotsB, Bb, cntA, slotsA, N2);

    // ---- conv3: [N2,64] @ [64,32] ----
    k_gemm<64, 32><<<N2 / 64, 256, 0, stream>>>(Bb, W3, H, N2);
    k_combine4<32><<<N2 / 32, 256, 0, stream>>>(H, cntA, slotsA, b3, A, N2 / 32);

    // ---- pool3: n=256 -> 128/graph ----
    k_score<32><<<N2 / 4, 256, 0, stream>>>(A, pw3, score, N2);
    k_topk_sort<256><<<BG, 128, 0, stream>>>(score, kvals, kperm, newid);
    k_pool_post<32><<<N3 / 32, 256, 0, stream>>>(A, kperm, kvals, newid,
                                                 cntA, slotsA, Bb, cntB, slotsB, N3);

    // ---- conv4: [N3,32] @ [32,16] ----
    k_gemm<32, 16><<<N3 / 64, 256, 0, stream>>>(Bb, W4, H, N3);
    k_combine4<16><<<N3 / 64, 256, 0, stream>>>(H, cntB, slotsB, b4, A, N3 / 64);

    // ---- final: mean-pool + linear ----
    k_final<<<BG, 128, 0, stream>>>(A, linW, linb, (float*)d_out);
}

// Round 7
// 346.576 us; speedup vs baseline: 1.8562x; 1.0001x over previous
//
#include <hip/hip_runtime.h>
#include <cstdint>
#include <cstddef>

#define CAP 64
#define EC  20480            // per-graph edge bucket capacity (expected 16384, sigma~124)
static constexpr int BG = 64;   // number of graphs

// ---------------- conv1 adjacency: bucket edges by graph ----------------
__global__ __launch_bounds__(256) void k_scatter(const int* __restrict__ src,
                                                 const int* __restrict__ dst,
                                                 int* __restrict__ gcur,
                                                 int2* __restrict__ ebuf) {
    __shared__ int lcnt[64], lbase[64], lpos[64];
    int tid = threadIdx.x;
    if (tid < 64) { lcnt[tid] = 0; lpos[tid] = 0; }
    __syncthreads();
    int e0 = (int)blockIdx.x * 1024;
    int ss[4], dd[4], gg[4];
    #pragma unroll
    for (int i = 0; i < 4; ++i) {
        int e = e0 + i * 256 + tid;
        ss[i] = src[e]; dd[i] = dst[e];
        gg[i] = dd[i] >> 10;
        atomicAdd(&lcnt[gg[i]], 1);
    }
    __syncthreads();
    if (tid < 64) lbase[tid] = atomicAdd(&gcur[tid], lcnt[tid]);
    __syncthreads();
    #pragma unroll
    for (int i = 0; i < 4; ++i) {
        int p = atomicAdd(&lpos[gg[i]], 1);
        int pos = lbase[gg[i]] + p;
        if (pos < EC) ebuf[(size_t)gg[i] * EC + pos] = make_int2(ss[i], dd[i]);
    }
}

// ---------------- conv1 adjacency: per-graph slot build (LDS counters) ----------------
__global__ __launch_bounds__(1024) void k_build(const int2* __restrict__ ebuf,
                                                const int* __restrict__ gcur,
                                                int* __restrict__ cnt,
                                                float* __restrict__ dis,
                                                int* __restrict__ slots) {
    __shared__ int lc[1024];
    int g = (int)blockIdx.x, tid = (int)threadIdx.x;
    lc[tid] = 0;
    __syncthreads();
    int ec = gcur[g]; if (ec > EC) ec = EC;
    const int2* eb = &ebuf[(size_t)g * EC];
    for (int e = tid; e < ec; e += 1024) {
        int2 sd = eb[e];
        int d = sd.y & 1023;
        int pos = atomicAdd(&lc[d], 1);
        if (pos < CAP) slots[(size_t)(g * 1024 + d) * CAP + pos] = sd.x;
    }
    __syncthreads();
    int c = lc[tid];
    cnt[g * 1024 + tid] = c;
    dis[g * 1024 + tid] = rsqrtf((float)(c + 1));
}

// ---------------- GEMM v2: 128-row x OUT tile, 512 thr, split-chunk layout ----------
template<int K, int OUT>
__global__ __launch_bounds__(512) void k_gemm2(const float* __restrict__ x,
                                               const float* __restrict__ W,
                                               float* __restrict__ h, int N) {
    constexpr int KT = 32;
    constexpr int RB = 128;
    constexpr int CC = OUT / 64;            // 2 (OUT=128) or 1 (OUT=64)
    constexpr int NW4 = (KT * OUT / 4) / 512;  // W float4 loads per thread
    __shared__ float Ws[KT * OUT];
    __shared__ float xs[KT * RB];           // transposed: xs[k*RB + row]
    int tid = (int)threadIdx.x;
    int tx = tid & 15;
    int ty = tid >> 4;                      // 0..31
    int row0 = (int)blockIdx.x * RB;
    const float4* W4 = (const float4*)W;

    float acc[4][CC * 4];
    #pragma unroll
    for (int r = 0; r < 4; ++r)
        #pragma unroll
        for (int c = 0; c < CC * 4; ++c) acc[r][c] = 0.f;

    int xr  = tid & 127;                    // staging row
    int xcb = tid >> 7;                     // 0..3 -> which pair of k-chunks

    for (int kt = 0; kt < K; kt += KT) {
        #pragma unroll
        for (int i = 0; i < NW4; ++i) {
            int idx = tid + i * 512;
            ((float4*)Ws)[idx] = W4[(size_t)kt * (OUT / 4) + idx];
        }
        const float4* xrow = (const float4*)(x + (size_t)(row0 + xr) * K + kt);
        #pragma unroll
        for (int i = 0; i < 2; ++i) {
            int c8 = xcb * 2 + i;           // float4 chunk within KT (0..7)
            float4 v = xrow[c8];
            xs[(c8 * 4 + 0) * RB + xr] = v.x;
            xs[(c8 * 4 + 1) * RB + xr] = v.y;
            xs[(c8 * 4 + 2) * RB + xr] = v.z;
            xs[(c8 * 4 + 3) * RB + xr] = v.w;
        }
        __syncthreads();
        #pragma unroll 8
        for (int k = 0; k < KT; ++k) {
            float4 av = *(const float4*)&xs[k * RB + 4 * ty];
            float4 b0 = *(const float4*)&Ws[k * OUT + 4 * tx];
            float a_[4] = {av.x, av.y, av.z, av.w};
            float b_[4] = {b0.x, b0.y, b0.z, b0.w};
            #pragma unroll
            for (int r = 0; r < 4; ++r)
                #pragma unroll
                for (int c = 0; c < 4; ++c)
                    acc[r][c] += a_[r] * b_[c];
            if constexpr (CC == 2) {
                float4 b1 = *(const float4*)&Ws[k * OUT + 64 + 4 * tx];
                float b2_[4] = {b1.x, b1.y, b1.z, b1.w};
                #pragma unroll
                for (int r = 0; r < 4; ++r)
                    #pragma unroll
                    for (int c = 0; c < 4; ++c)
                        acc[r][4 + c] += a_[r] * b2_[c];
            }
        }
        __syncthreads();
    }
    float4* h4 = (float4*)h;
    #pragma unroll
    for (int rr = 0; rr < 4; ++rr) {
        int row = row0 + 4 * ty + rr;
        float4 o0;
        o0.x = acc[rr][0]; o0.y = acc[rr][1]; o0.z = acc[rr][2]; o0.w = acc[rr][3];
        h4[(size_t)row * (OUT / 4) + tx] = o0;
        if constexpr (CC == 2) {
            float4 o1;
            o1.x = acc[rr][4]; o1.y = acc[rr][5]; o1.z = acc[rr][6]; o1.w = acc[rr][7];
            h4[(size_t)row * (OUT / 4) + 16 + tx] = o1;
        }
    }
}

// ---------------- GEMM v1 (kept for small OUT): LDS tiled, reg-blocked ----------------
template<int K, int OUT>
__global__ __launch_bounds__(256) void k_gemm(const float* __restrict__ x,
                                              const float* __restrict__ W,
                                              float* __restrict__ h, int N) {
    constexpr int ROWS = 64;
    constexpr int KT   = (K >= 64) ? 64 : K;
    constexpr int CT   = OUT / 4;
    constexpr int RT   = 256 / CT;
    constexpr int RPT  = ROWS / RT;
    constexpr int XP   = ROWS + 4;
    __shared__ float Ws[KT * OUT];
    __shared__ float xs[KT * XP];
    int tid  = threadIdx.x;
    int row0 = blockIdx.x * ROWS;
    int c    = tid % CT;
    int rt   = tid / CT;
    float acc[RPT][4];
    for (int r = 0; r < RPT; ++r)
        for (int j = 0; j < 4; ++j) acc[r][j] = 0.f;

    for (int kt = 0; kt < K; kt += KT) {
        for (int i = tid; i < KT * OUT; i += 256)
            Ws[i] = W[(size_t)(kt + i / OUT) * OUT + (i % OUT)];
        for (int i = tid; i < ROWS * KT; i += 256) {
            int r = i / KT, k = i % KT;
            xs[k * XP + r] = x[(size_t)(row0 + r) * K + kt + k];
        }
        __syncthreads();
        for (int k = 0; k < KT; ++k) {
            float4 wv = *(const float4*)&Ws[k * OUT + 4 * c];
            const float* xk = &xs[k * XP + rt * RPT];
            #pragma unroll
            for (int r = 0; r < RPT; ++r) {
                float xv = xk[r];
                acc[r][0] += xv * wv.x;
                acc[r][1] += xv * wv.y;
                acc[r][2] += xv * wv.z;
                acc[r][3] += xv * wv.w;
            }
        }
        __syncthreads();
    }
    for (int r = 0; r < RPT; ++r) {
        int row = row0 + rt * RPT + r;
        float4 o;
        o.x = acc[r][0]; o.y = acc[r][1]; o.z = acc[r][2]; o.w = acc[r][3];
        *(float4*)&h[(size_t)row * OUT + 4 * c] = o;
    }
}

// ---------------- combine: out = relu(agg + h*dis^2 + b) ----------------
// dis[] precomputed (same rsqrtf values as before -> bit-identical); 8-deep
// neighbor unroll, += sequence strictly j-ascending (bitwise same as 4-deep).
template<int OUT>
__global__ __launch_bounds__(256) void k_combine4(const float* __restrict__ h,
                                                  const int* __restrict__ cnt,
                                                  const float* __restrict__ dis,
                                                  const int* __restrict__ slots,
                                                  const float* __restrict__ b,
                                                  float* __restrict__ out, int nblocks) {
    constexpr int TPN = OUT / 4;
    constexpr int NPB = 256 / TPN;
    constexpr int S4  = OUT / 4;
    int bid = (int)blockIdx.x;
    int wb  = (bid & 7) * (nblocks >> 3) + (bid >> 3);   // XCD-grouped swizzle
    int i   = wb * NPB + (int)threadIdx.x / TPN;
    int fq  = (int)threadIdx.x % TPN;
    const float4* h4 = (const float4*)h;
    int ci = cnt[i];
    float di = dis[i];
    int c = ci > CAP ? CAP : ci;
    float4 hv = h4[(size_t)i * S4 + fq];
    float4 bv = *(const float4*)(b + 4 * fq);
    float4 acc;
    acc.x = hv.x * di * di + bv.x;
    acc.y = hv.y * di * di + bv.y;
    acc.z = hv.z * di * di + bv.z;
    acc.w = hv.w * di * di + bv.w;
    const int* sl = &slots[(size_t)i * CAP];
    int j = 0;
    for (; j + 8 <= c; j += 8) {
        int4 sa = *(const int4*)(sl + j);
        int4 sb = *(const int4*)(sl + j + 4);
        float c0 = dis[sa.x] * di, c1 = dis[sa.y] * di;
        float c2 = dis[sa.z] * di, c3 = dis[sa.w] * di;
        float c4 = dis[sb.x] * di, c5 = dis[sb.y] * di;
        float c6 = dis[sb.z] * di, c7 = dis[sb.w] * di;
        float4 v0 = h4[(size_t)sa.x * S4 + fq];
        float4 v1 = h4[(size_t)sa.y * S4 + fq];
        float4 v2 = h4[(size_t)sa.z * S4 + fq];
        float4 v3 = h4[(size_t)sa.w * S4 + fq];
        float4 v4 = h4[(size_t)sb.x * S4 + fq];
        float4 v5 = h4[(size_t)sb.y * S4 + fq];
        float4 v6 = h4[(size_t)sb.z * S4 + fq];
        float4 v7 = h4[(size_t)sb.w * S4 + fq];
        acc.x += v0.x * c0; acc.y += v0.y * c0; acc.z += v0.z * c0; acc.w += v0.w * c0;
        acc.x += v1.x * c1; acc.y += v1.y * c1; acc.z += v1.z * c1; acc.w += v1.w * c1;
        acc.x += v2.x * c2; acc.y += v2.y * c2; acc.z += v2.z * c2; acc.w += v2.w * c2;
        acc.x += v3.x * c3; acc.y += v3.y * c3; acc.z += v3.z * c3; acc.w += v3.w * c3;
        acc.x += v4.x * c4; acc.y += v4.y * c4; acc.z += v4.z * c4; acc.w += v4.w * c4;
        acc.x += v5.x * c5; acc.y += v5.y * c5; acc.z += v5.z * c5; acc.w += v5.w * c5;
        acc.x += v6.x * c6; acc.y += v6.y * c6; acc.z += v6.z * c6; acc.w += v6.w * c6;
        acc.x += v7.x * c7; acc.y += v7.y * c7; acc.z += v7.z * c7; acc.w += v7.w * c7;
    }
    for (; j + 4 <= c; j += 4) {
        int4 s4 = *(const int4*)(sl + j);
        float c0 = dis[s4.x] * di, c1 = dis[s4.y] * di;
        float c2 = dis[s4.z] * di, c3 = dis[s4.w] * di;
        float4 v0 = h4[(size_t)s4.x * S4 + fq];
        float4 v1 = h4[(size_t)s4.y * S4 + fq];
        float4 v2 = h4[(size_t)s4.z * S4 + fq];
        float4 v3 = h4[(size_t)s4.w * S4 + fq];
        acc.x += v0.x * c0; acc.y += v0.y * c0; acc.z += v0.z * c0; acc.w += v0.w * c0;
        acc.x += v1.x * c1; acc.y += v1.y * c1; acc.z += v1.z * c1; acc.w += v1.w * c1;
        acc.x += v2.x * c2; acc.y += v2.y * c2; acc.z += v2.z * c2; acc.w += v2.w * c2;
        acc.x += v3.x * c3; acc.y += v3.y * c3; acc.z += v3.z * c3; acc.w += v3.w * c3;
    }
    for (; j < c; ++j) {
        int s = sl[j];
        float co = dis[s] * di;
        float4 v = h4[(size_t)s * S4 + fq];
        acc.x += v.x * co; acc.y += v.y * co; acc.z += v.z * co; acc.w += v.w * co;
    }
    float4 o;
    o.x = fmaxf(acc.x, 0.f);
    o.y = fmaxf(acc.y, 0.f);
    o.z = fmaxf(acc.z, 0.f);
    o.w = fmaxf(acc.w, 0.f);
    ((float4*)out)[(size_t)i * S4 + fq] = o;
}

// ---------------- scores: tanh((x . pw)/||pw||) (unchanged numerics) ----------------
template<int DIM>
__global__ void k_score(const float* __restrict__ x, const float* __restrict__ pw,
                        float* __restrict__ score, int N) {
    int wave = threadIdx.x >> 6;
    int lane = threadIdx.x & 63;
    int node = blockIdx.x * (blockDim.x >> 6) + wave;
    if (node >= N) return;
    float sd = 0.f, sn = 0.f;
    for (int k = lane; k < DIM; k += 64) {
        float w = pw[k];
        sd += x[(size_t)node * DIM + k] * w;
        sn += w * w;
    }
    #pragma unroll
    for (int off = 32; off > 0; off >>= 1) {
        sd += __shfl_down(sd, off);
        sn += __shfl_down(sn, off);
    }
    if (lane == 0) score[node] = tanhf(sd * rsqrtf(sn));
}

// ---------------- top-k sort (per-graph bitonic in LDS) ----------------
template<int n>
__global__ void k_topk_sort(const float* __restrict__ score,
                            float* __restrict__ kvals, int* __restrict__ kperm,
                            int* __restrict__ newid) {
    constexpr int k = n / 2;
    __shared__ float ss[n];
    __shared__ int   si[n];
    int g = blockIdx.x;
    int t = threadIdx.x;                    // 0 .. n/2-1
    for (int i = t; i < n; i += n / 2) {
        ss[i] = score[g * n + i];
        si[i] = i;
        newid[g * n + i] = -1;
    }
    for (int size = 2; size <= n; size <<= 1) {
        for (int stride = size >> 1; stride > 0; stride >>= 1) {
            __syncthreads();
            int lo = 2 * t - (t & (stride - 1));
            int hi = lo + stride;
            float sa = ss[lo], sb = ss[hi];
            int   ia = si[lo], ib = si[hi];
            bool aFirst = (sa > sb) || (sa == sb && ia < ib);  // desc, idx tiebreak
            bool desc = ((lo & size) == 0);
            if (desc ? !aFirst : aFirst) {
                ss[lo] = sb; ss[hi] = sa;
                si[lo] = ib; si[hi] = ia;
            }
        }
    }
    __syncthreads();
    for (int r = t; r < k; r += n / 2) {
        newid[g * n + si[r]] = g * k + r;
        kperm[g * k + r] = g * n + si[r];   // global source row (old id)
        kvals[g * k + r] = ss[r];
    }
}

// ---------------- pool post: gather+scale rows AND derive next-layer adjacency ----
template<int DIM>
__global__ __launch_bounds__(256) void k_pool_post(const float* __restrict__ x,
                                                   const int* __restrict__ kperm,
                                                   const float* __restrict__ kvals,
                                                   const int* __restrict__ newid,
                                                   const int* __restrict__ cnt_old,
                                                   const int* __restrict__ slots_old,
                                                   float* __restrict__ xnew,
                                                   int* __restrict__ cnt_new,
                                                   float* __restrict__ dis_new,
                                                   int* __restrict__ slots_new,
                                                   int Nnew) {
    constexpr int S4  = DIM / 4;
    constexpr int RPB = 32;             // rows per block (8 threads per row)
    int r = (int)blockIdx.x * RPB + (int)threadIdx.x / 8;
    int q = (int)threadIdx.x % 8;
    if (r >= Nnew) return;
    int old = kperm[r];
    float s = kvals[r];
    const float4* x4 = (const float4*)x;
    float4* o4 = (float4*)xnew;
    #pragma unroll
    for (int it = 0; it < (S4 + 7) / 8; ++it) {
        int idx = it * 8 + q;
        if (S4 % 8 == 0 || idx < S4) {
            float4 v = x4[(size_t)old * S4 + idx];
            float4 o;
            o.x = v.x * s; o.y = v.y * s; o.z = v.z * s; o.w = v.w * s;
            o4[(size_t)r * S4 + idx] = o;
        }
    }
    if (q == 0) {
        int c = cnt_old[old];
        if (c > CAP) c = CAP;
        const int* sl = &slots_old[(size_t)old * CAP];
        int w = 0;
        for (int j = 0; j < c; ++j) {
            int ns = newid[sl[j]];
            if (ns >= 0) slots_new[(size_t)r * CAP + (w++)] = ns;
        }
        cnt_new[r] = w;
        dis_new[r] = rsqrtf((float)(w + 1));
    }
}

// ---------------- final: per-graph mean -> linear -> *100 ----------------
__global__ void k_final(const float* __restrict__ x, const float* __restrict__ linW,
                        const float* __restrict__ linb, float* __restrict__ out) {
    int g = blockIdx.x;
    int t = threadIdx.x;                    // 128 threads = 128 nodes/graph
    const float* xr = &x[(size_t)(g * 128 + t) * 16];
    float p = 0.f;
    #pragma unroll
    for (int f = 0; f < 16; ++f) p += xr[f] * linW[f];
    #pragma unroll
    for (int off = 32; off > 0; off >>= 1) p += __shfl_down(p, off);
    __shared__ float wsum[2];
    if ((t & 63) == 0) wsum[t >> 6] = p;
    __syncthreads();
    if (t == 0) out[g] = ((wsum[0] + wsum[1]) * (1.f / 128.f) + linb[0]) * 100.f;
}

// ---------------- launch ----------------
extern "C" void kernel_launch(void* const* d_in, const int* in_sizes, int n_in,
                              void* d_out, int out_size, void* d_ws, size_t ws_size,
                              hipStream_t stream) {
    const float* x0  = (const float*)d_in[0];
    const int*   ei  = (const int*)d_in[1];
    const int    E   = in_sizes[1] / 2;     // 1048576
    const int    N0  = in_sizes[0] / 128;   // 65536
    const float* W1  = (const float*)d_in[3];
    const float* b1  = (const float*)d_in[4];
    const float* pw1 = (const float*)d_in[5];
    const float* W2  = (const float*)d_in[6];
    const float* b2  = (const float*)d_in[7];
    const float* pw2 = (const float*)d_in[8];
    const float* W3  = (const float*)d_in[9];
    const float* b3  = (const float*)d_in[10];
    const float* pw3 = (const float*)d_in[11];
    const float* W4  = (const float*)d_in[12];
    const float* b4  = (const float*)d_in[13];
    const float* linW = (const float*)d_in[14];
    const float* linb = (const float*)d_in[15];

    char* ws = (char*)d_ws;
    size_t off = 0;
    float* A      = (float*)(ws + off); off += (size_t)N0 * 128 * 4;       // 32 MB
    float* H      = (float*)(ws + off); off += (size_t)N0 * 128 * 4;       // 32 MB
    float* Bb     = (float*)(ws + off); off += (size_t)(N0 / 2) * 128 * 4; // 16 MB
    int*   slotsA = (int*)(ws + off);   off += (size_t)N0 * CAP * 4;       // 16 MB
    int*   slotsB = (int*)(ws + off);   off += (size_t)(N0 / 2) * CAP * 4; // 8 MB
    int2*  ebuf   = (int2*)(ws + off);  off += (size_t)BG * EC * 8;        // 10.5 MB
    int*   cntA   = (int*)(ws + off);   off += (size_t)N0 * 4;
    int*   cntB   = (int*)(ws + off);   off += (size_t)(N0 / 2) * 4;
    float* disA   = (float*)(ws + off); off += (size_t)N0 * 4;
    float* disB   = (float*)(ws + off); off += (size_t)(N0 / 2) * 4;
    float* score  = (float*)(ws + off); off += (size_t)N0 * 4;
    int*   newid  = (int*)(ws + off);   off += (size_t)N0 * 4;
    int*   kperm  = (int*)(ws + off);   off += (size_t)(N0 / 2) * 4;
    float* kvals  = (float*)(ws + off); off += (size_t)(N0 / 2) * 4;
    int*   gcur   = (int*)(ws + off);   off += 64 * 4;

    const int* src0 = ei;
    const int* dst0 = ei + E;

    const int N1 = N0 / 2;   // 32768
    const int N2 = N1 / 2;   // 16384
    const int N3 = N2 / 2;   // 8192

    // ---- conv1 adjacency: bucket by graph, then per-graph LDS build ----
    hipMemsetAsync(gcur, 0, 64 * 4, stream);
    k_scatter<<<E / 1024, 256, 0, stream>>>(src0, dst0, gcur, ebuf);
    k_build<<<BG, 1024, 0, stream>>>(ebuf, gcur, cntA, disA, slotsA);

    // ---- conv1: [N0,128] @ [128,128] ----
    k_gemm2<128, 128><<<N0 / 128, 512, 0, stream>>>(x0, W1, H, N0);
    k_combine4<128><<<N0 / 8, 256, 0, stream>>>(H, cntA, disA, slotsA, b1, A, N0 / 8);

    // ---- pool1: n=1024 -> 512/graph ----
    k_score<128><<<N0 / 4, 256, 0, stream>>>(A, pw1, score, N0);
    k_topk_sort<1024><<<BG, 512, 0, stream>>>(score, kvals, kperm, newid);
    k_pool_post<128><<<N1 / 32, 256, 0, stream>>>(A, kperm, kvals, newid,
                                                  cntA, slotsA, Bb, cntB, disB, slotsB, N1);

    // ---- conv2: [N1,128] @ [128,64] ----
    k_gemm2<128, 64><<<N1 / 128, 512, 0, stream>>>(Bb, W2, H, N1);
    k_combine4<64><<<N1 / 16, 256, 0, stream>>>(H, cntB, disB, slotsB, b2, A, N1 / 16);

    // ---- pool2: n=512 -> 256/graph ----
    k_score<64><<<N1 / 4, 256, 0, stream>>>(A, pw2, score, N1);
    k_topk_sort<512><<<BG, 256, 0, stream>>>(score, kvals, kperm, newid);
    k_pool_post<64><<<N2 / 32, 256, 0, stream>>>(A, kperm, kvals, newid,
                                                 cntB, slotsB, Bb, cntA, disA, slotsA, N2);

    // ---- conv3: [N2,64] @ [64,32] ----
    k_gemm<64, 32><<<N2 / 64, 256, 0, stream>>>(Bb, W3, H, N2);
    k_combine4<32><<<N2 / 32, 256, 0, stream>>>(H, cntA, disA, slotsA, b3, A, N2 / 32);

    // ---- pool3: n=256 -> 128/graph ----
    k_score<32><<<N2 / 4, 256, 0, stream>>>(A, pw3, score, N2);
    k_topk_sort<256><<<BG, 128, 0, stream>>>(score, kvals, kperm, newid);
    k_pool_post<32><<<N3 / 32, 256, 0, stream>>>(A, kperm, kvals, newid,
                                                 cntA, slotsA, Bb, cntB, disB, slotsB, N3);

    // ---- conv4: [N3,32] @ [32,16] ----
    k_gemm<32, 16><<<N3 / 64, 256, 0, stream>>>(Bb, W4, H, N3);
    k_combine4<16><<<N3 / 64, 256, 0, stream>>>(H, cntB, disB, slotsB, b4, A, N3 / 64);

    // ---- final: mean-pool + linear ----
    k_final<<<BG, 128, 0, stream>>>(A, linW, linb, (float*)d_out);
}